// Round 3
// baseline (123.047 us; speedup 1.0000x reference)
//
#include <hip/hip_runtime.h>
#include <hip/hip_bf16.h>

#define N_TOK 8192

typedef float f32x4  __attribute__((ext_vector_type(4)));
typedef float f32x16 __attribute__((ext_vector_type(16)));
typedef short bf16x8 __attribute__((ext_vector_type(8)));
typedef unsigned int u32x4 __attribute__((ext_vector_type(4)));

__device__ inline short f2bf(float f) {
    union { __hip_bfloat16 h; short s; } u;
    u.h = __float2bfloat16(f);
    return u.s;
}
__device__ inline unsigned cvtpk(float lo, float hi) {
    unsigned r;
    asm("v_cvt_pk_bf16_f32 %0, %1, %2" : "=v"(r) : "v"(lo), "v"(hi));
    return r;
}
__device__ inline void plswap(unsigned &a, unsigned &b) {
    asm("v_permlane32_swap_b32 %0, %1" : "+v"(a), "+v"(b));
}

// ---------------- kernel 0: weight convert/transpose ----------------
__global__ void conv_kernel(const float* __restrict__ Wqkv,
                            const float* __restrict__ Wout,
                            __hip_bfloat16* __restrict__ Wt,      // [192][1024]
                            __hip_bfloat16* __restrict__ WoT) {   // [1024][64]
    int idx = blockIdx.x * 256 + threadIdx.x;
    if (idx < 192 * 1024) {
        int n = idx >> 10, k = idx & 1023;
        Wt[idx] = __float2bfloat16(Wqkv[k * 192 + n]);
    } else {
        int j = idx - 192 * 1024;
        if (j < 1024 * 64) {
            int n = j >> 6, k = j & 63;
            WoT[j] = __float2bfloat16(Wout[k * 1024 + n]);
        }
    }
}

// ---------------- kernel 1: qkv = x @ Wqkv -------------------------
// grid 512, block 256 (4 waves). 16 rows/block, wave w owns nt = 3w..3w+2.
// Swapped mfma(Wfrag, xfrag): lane holds 4 consecutive out-cols of one row
// -> short4 stores. Q pre-scaled by 0.125*log2(e).
__global__ __launch_bounds__(256) void qkv_kernel(
    const float* __restrict__ x,
    const __hip_bfloat16* __restrict__ Wt,
    __hip_bfloat16* __restrict__ Qb,    // [8192][64]
    __hip_bfloat16* __restrict__ Kb,    // [8192][64]
    __hip_bfloat16* __restrict__ Vt) {  // [64][8192]
    __shared__ __hip_bfloat16 sV[64][20];
    const int tid = threadIdx.x;
    const int w = tid >> 6, lane = tid & 63;
    const int l16 = lane & 15, lq = lane >> 4;
    const int m0 = blockIdx.x * 16;

    f32x4 acc[3];
    #pragma unroll
    for (int j = 0; j < 3; ++j) acc[j] = (f32x4)0.f;

    const float* xrow = x + (size_t)(m0 + l16) * 1024;
    for (int ks = 0; ks < 32; ++ks) {
        const int kb = ks * 32 + 8 * lq;
        float4 f0 = *reinterpret_cast<const float4*>(xrow + kb);
        float4 f1 = *reinterpret_cast<const float4*>(xrow + kb + 4);
        bf16x8 a;
        a[0]=f2bf(f0.x); a[1]=f2bf(f0.y); a[2]=f2bf(f0.z); a[3]=f2bf(f0.w);
        a[4]=f2bf(f1.x); a[5]=f2bf(f1.y); a[6]=f2bf(f1.z); a[7]=f2bf(f1.w);
        #pragma unroll
        for (int j = 0; j < 3; ++j) {
            bf16x8 b = *reinterpret_cast<const bf16x8*>(
                Wt + (size_t)((w * 3 + j) * 16 + l16) * 1024 + kb);
            acc[j] = __builtin_amdgcn_mfma_f32_16x16x32_bf16(b, a, acc[j], 0, 0, 0);
        }
    }
    const int row = m0 + l16;
    #pragma unroll
    for (int j = 0; j < 3; ++j) {
        const int nt = w * 3 + j;
        const int nb = nt * 16 + 4 * lq;   // 4 consecutive out cols
        if (nt < 4) {
            short4 qs;
            qs.x = f2bf(acc[j][0] * 0.18033688011112042f);
            qs.y = f2bf(acc[j][1] * 0.18033688011112042f);
            qs.z = f2bf(acc[j][2] * 0.18033688011112042f);
            qs.w = f2bf(acc[j][3] * 0.18033688011112042f);
            *reinterpret_cast<short4*>(Qb + (size_t)row * 64 + nb) = qs;
        } else if (nt < 8) {
            short4 ks4;
            ks4.x = f2bf(acc[j][0]); ks4.y = f2bf(acc[j][1]);
            ks4.z = f2bf(acc[j][2]); ks4.w = f2bf(acc[j][3]);
            *reinterpret_cast<short4*>(Kb + (size_t)row * 64 + (nb - 64)) = ks4;
        } else {
            #pragma unroll
            for (int r = 0; r < 4; ++r)
                sV[nb + r - 128][l16] = __float2bfloat16(acc[j][r]);
        }
    }
    __syncthreads();
    const int vc = tid >> 2, vi = tid & 3;
    short4 vv = *reinterpret_cast<const short4*>(&sV[vc][vi * 4]);
    *reinterpret_cast<short4*>(Vt + (size_t)vc * N_TOK + m0 + vi * 4) = vv;
}

// ---------------- kernel 2: causal flash attention -----------------
// grid 512: (pair p = bid>>2, split s = bid&3). Tiles p and 255-p.
// 8 waves; wave slot = s*8+w handles kv chunks c = slot + 32*i (64 kv each).
// Swapped QK^T (S^T = K Q^T); softmax in-register, base-2; tree reductions.
__global__ __launch_bounds__(512) void attn_kernel(
    const __hip_bfloat16* __restrict__ Qb,
    const __hip_bfloat16* __restrict__ Kb,
    const __hip_bfloat16* __restrict__ Vt,
    float* __restrict__ Part) {  // [256 tiles][4 splits][2112] f32
    __shared__ float sO[8][64][32];
    __shared__ float sM[8][32];
    __shared__ float sL[8][32];
    const int tid = threadIdx.x;
    const int w = tid >> 6, lane = tid & 63;
    const int l31 = lane & 31, hi = lane >> 5;
    const int p = blockIdx.x >> 2, s = blockIdx.x & 3;
    const int slot = s * 8 + w;

    for (int ti = 0; ti < 2; ++ti) {
        const int t = ti ? (255 - p) : p;
        const int q0 = t * 32;
        const int Ct = (q0 + 95) >> 6;   // ceil((q0+32)/64)
        const int qabs = q0 + l31;

        bf16x8 qf[4];
        const __hip_bfloat16* qrow = Qb + (size_t)(q0 + l31) * 64 + 8 * hi;
        #pragma unroll
        for (int c = 0; c < 4; ++c)
            qf[c] = *reinterpret_cast<const bf16x8*>(qrow + c * 16);

        float m = -3.0e38f, l = 0.f;
        f32x16 Oa = (f32x16)0.f, Oc = (f32x16)0.f;

        for (int c = slot; c < Ct; c += 32) {
            const int kv0 = c * 64;
            const __hip_bfloat16* kbase = Kb + (size_t)(kv0 + l31) * 64 + 8 * hi;
            bf16x8 ka[4], kb2[4];
            #pragma unroll
            for (int kc = 0; kc < 4; ++kc) {
                ka[kc]  = *reinterpret_cast<const bf16x8*>(kbase + kc * 16);
                kb2[kc] = *reinterpret_cast<const bf16x8*>(kbase + 32 * 64 + kc * 16);
            }
            f32x16 Sa = (f32x16)0.f, Sb = (f32x16)0.f;
            #pragma unroll
            for (int kc = 0; kc < 4; ++kc)
                Sa = __builtin_amdgcn_mfma_f32_32x32x16_bf16(ka[kc], qf[kc], Sa, 0, 0, 0);
            #pragma unroll
            for (int kc = 0; kc < 4; ++kc)
                Sb = __builtin_amdgcn_mfma_f32_32x32x16_bf16(kb2[kc], qf[kc], Sb, 0, 0, 0);

            if (kv0 + 64 > q0) {  // only near-diagonal chunks need masking
                #pragma unroll
                for (int r = 0; r < 16; ++r) {
                    const int rowk = (r & 3) + 8 * (r >> 2) + 4 * hi;
                    if (kv0 + rowk > qabs)      Sa[r] = -1.0e30f;
                    if (kv0 + 32 + rowk > qabs) Sb[r] = -1.0e30f;
                }
            }

            // tree max (depth 5)
            float v8[8];
            #pragma unroll
            for (int j = 0; j < 8; ++j)
                v8[j] = fmaxf(fmaxf(Sa[2*j], Sa[2*j+1]), fmaxf(Sb[2*j], Sb[2*j+1]));
            #pragma unroll
            for (int j = 0; j < 4; ++j) v8[j] = fmaxf(v8[j], v8[j+4]);
            float mx = fmaxf(fmaxf(v8[0], v8[2]), fmaxf(v8[1], v8[3]));
            mx = fmaxf(mx, __shfl_xor(mx, 32));
            const float mnew = fmaxf(m, mx);
            const float fac = exp2f(m - mnew);
            #pragma unroll
            for (int r = 0; r < 16; ++r) Sa[r] = exp2f(Sa[r] - mnew);
            #pragma unroll
            for (int r = 0; r < 16; ++r) Sb[r] = exp2f(Sb[r] - mnew);
            // tree sum
            float s8[8];
            #pragma unroll
            for (int j = 0; j < 8; ++j)
                s8[j] = (Sa[2*j] + Sa[2*j+1]) + (Sb[2*j] + Sb[2*j+1]);
            #pragma unroll
            for (int j = 0; j < 4; ++j) s8[j] += s8[j+4];
            float ps = (s8[0] + s8[2]) + (s8[1] + s8[3]);
            ps += __shfl_xor(ps, 32);
            l = l * fac + ps;
            m = mnew;
            #pragma unroll
            for (int r = 0; r < 16; ++r) { Oa[r] *= fac; Oc[r] *= fac; }

            // P^T -> bf16 B-fragments via cvt_pk + permlane32_swap (T12)
            bf16x8 F0, F1, F2, F3;
            {
                unsigned a0 = cvtpk(Sa[0], Sa[1]),  a1 = cvtpk(Sa[2], Sa[3]);
                unsigned a2 = cvtpk(Sa[4], Sa[5]),  a3 = cvtpk(Sa[6], Sa[7]);
                plswap(a0, a2); plswap(a1, a3);
                u32x4 w0; w0[0]=a0; w0[1]=a1; w0[2]=a2; w0[3]=a3;
                F0 = __builtin_bit_cast(bf16x8, w0);
                unsigned b0 = cvtpk(Sa[8], Sa[9]),  b1 = cvtpk(Sa[10], Sa[11]);
                unsigned b2 = cvtpk(Sa[12], Sa[13]), b3 = cvtpk(Sa[14], Sa[15]);
                plswap(b0, b2); plswap(b1, b3);
                u32x4 w1; w1[0]=b0; w1[1]=b1; w1[2]=b2; w1[3]=b3;
                F1 = __builtin_bit_cast(bf16x8, w1);
                unsigned c0 = cvtpk(Sb[0], Sb[1]),  c1 = cvtpk(Sb[2], Sb[3]);
                unsigned c2 = cvtpk(Sb[4], Sb[5]),  c3 = cvtpk(Sb[6], Sb[7]);
                plswap(c0, c2); plswap(c1, c3);
                u32x4 w2; w2[0]=c0; w2[1]=c1; w2[2]=c2; w2[3]=c3;
                F2 = __builtin_bit_cast(bf16x8, w2);
                unsigned d0 = cvtpk(Sb[8], Sb[9]),  d1 = cvtpk(Sb[10], Sb[11]);
                unsigned d2 = cvtpk(Sb[12], Sb[13]), d3 = cvtpk(Sb[14], Sb[15]);
                plswap(d0, d2); plswap(d1, d3);
                u32x4 w3; w3[0]=d0; w3[1]=d1; w3[2]=d2; w3[3]=d3;
                F3 = __builtin_bit_cast(bf16x8, w3);
            }
            const __hip_bfloat16* vbase = Vt + (size_t)l31 * N_TOK + kv0 + 8 * hi;
            bf16x8 Fa[4] = {F0, F1, F2, F3};
            #pragma unroll
            for (int ks = 0; ks < 4; ++ks) {
                bf16x8 v0 = *reinterpret_cast<const bf16x8*>(vbase + ks * 16);
                bf16x8 v1 = *reinterpret_cast<const bf16x8*>(vbase + (size_t)32 * N_TOK + ks * 16);
                Oa = __builtin_amdgcn_mfma_f32_32x32x16_bf16(v0, Fa[ks], Oa, 0, 0, 0);
                Oc = __builtin_amdgcn_mfma_f32_32x32x16_bf16(v1, Fa[ks], Oc, 0, 0, 0);
            }
        }

        if (hi == 0) { sM[w][l31] = m; sL[w][l31] = l; }
        #pragma unroll
        for (int r = 0; r < 16; ++r) {
            const int d = (r & 3) + 8 * (r >> 2) + 4 * hi;
            sO[w][d][l31]      = Oa[r];
            sO[w][d + 32][l31] = Oc[r];
        }
        __syncthreads();

        float* pb = Part + (size_t)(t * 4 + s) * 2112;
        for (int e = tid; e < 2048; e += 512) {
            const int d = e >> 5, qq = e & 31;
            float mb = -3.0e38f;
            #pragma unroll
            for (int wi = 0; wi < 8; ++wi) mb = fmaxf(mb, sM[wi][qq]);
            float lb = 0.f, ob = 0.f;
            #pragma unroll
            for (int wi = 0; wi < 8; ++wi) {
                const float sc = exp2f(sM[wi][qq] - mb);
                lb += sL[wi][qq] * sc;
                ob += sO[wi][d][qq] * sc;
            }
            pb[e] = ob;
            if (d == 0) { pb[2048 + qq] = mb; pb[2080 + qq] = lb; }
        }
        __syncthreads();
    }
}

// ---------------- kernel 2b: merge the 4 kv-split partials ---------
__global__ __launch_bounds__(256) void merge_kernel(
    const float* __restrict__ Part, __hip_bfloat16* __restrict__ Ob) {
    const int t = blockIdx.x, q0 = t * 32;
    const float* pp = Part + (size_t)(t * 4) * 2112;
    for (int e = threadIdx.x; e < 2048; e += 256) {
        const int qq = e >> 6, d = e & 63;
        float mm = -3.0e38f;
        #pragma unroll
        for (int si = 0; si < 4; ++si) mm = fmaxf(mm, pp[si * 2112 + 2048 + qq]);
        float ll = 0.f, oo = 0.f;
        #pragma unroll
        for (int si = 0; si < 4; ++si) {
            const float sc = exp2f(pp[si * 2112 + 2048 + qq] - mm);
            ll += pp[si * 2112 + 2080 + qq] * sc;
            oo += pp[si * 2112 + d * 32 + qq] * sc;
        }
        Ob[(size_t)(q0 + qq) * 64 + d] = __float2bfloat16(oo / ll);
    }
}

// ---------------- kernel 3: out = O @ Wout + bout ------------------
// Swapped mfma(Wfrag, Ofrag): lane owns 4 consecutive cols of one row
// -> one float4 store per tile per lane.
__global__ __launch_bounds__(256) void out_kernel(
    const __hip_bfloat16* __restrict__ Ob,
    const __hip_bfloat16* __restrict__ WoT,
    const float* __restrict__ bout,
    float* __restrict__ out) {
    const int tid = threadIdx.x;
    const int w = tid >> 6, lane = tid & 63;
    const int l16 = lane & 15, lq = lane >> 4;
    const int m0 = blockIdx.x * 64 + w * 16;
    const int n0 = blockIdx.y * 256;

    const __hip_bfloat16* orow = Ob + (size_t)(m0 + l16) * 64;
    bf16x8 a0 = *reinterpret_cast<const bf16x8*>(orow + 8 * lq);
    bf16x8 a1 = *reinterpret_cast<const bf16x8*>(orow + 32 + 8 * lq);

    const int row = m0 + l16;
    for (int nt = 0; nt < 16; ++nt) {
        const __hip_bfloat16* wrow = WoT + (size_t)(n0 + nt * 16 + l16) * 64;
        bf16x8 b0 = *reinterpret_cast<const bf16x8*>(wrow + 8 * lq);
        bf16x8 b1 = *reinterpret_cast<const bf16x8*>(wrow + 32 + 8 * lq);
        f32x4 acc = (f32x4)0.f;
        acc = __builtin_amdgcn_mfma_f32_16x16x32_bf16(b0, a0, acc, 0, 0, 0);
        acc = __builtin_amdgcn_mfma_f32_16x16x32_bf16(b1, a1, acc, 0, 0, 0);
        const int nb = n0 + nt * 16 + 4 * lq;
        float4 bb = *reinterpret_cast<const float4*>(bout + nb);
        float4 res;
        res.x = acc[0] + bb.x; res.y = acc[1] + bb.y;
        res.z = acc[2] + bb.z; res.w = acc[3] + bb.w;
        *reinterpret_cast<float4*>(out + (size_t)row * 1024 + nb) = res;
    }
}

// ---------------- launch -------------------------------------------
extern "C" void kernel_launch(void* const* d_in, const int* in_sizes, int n_in,
                              void* d_out, int out_size, void* d_ws, size_t ws_size,
                              hipStream_t stream) {
    const float* x    = (const float*)d_in[0];
    const float* Wqkv = (const float*)d_in[1];
    const float* Wout = (const float*)d_in[2];
    const float* bout = (const float*)d_in[3];
    float* out = (float*)d_out;

    char* ws = (char*)d_ws;
    __hip_bfloat16* Wt  = (__hip_bfloat16*)(ws);                 // 393216 B
    __hip_bfloat16* WoT = (__hip_bfloat16*)(ws + 393216);        // 131072 B
    __hip_bfloat16* Qb  = (__hip_bfloat16*)(ws + 524288);        // 1 MiB
    __hip_bfloat16* Kb  = (__hip_bfloat16*)(ws + 1572864);       // 1 MiB
    __hip_bfloat16* Vt  = (__hip_bfloat16*)(ws + 2621440);       // 1 MiB
    __hip_bfloat16* Ob  = (__hip_bfloat16*)(ws + 3670016);       // 1 MiB
    float*          Part = (float*)(ws + 4718592);               // 8.65 MB

    conv_kernel<<<1024, 256, 0, stream>>>(Wqkv, Wout, Wt, WoT);
    qkv_kernel<<<512, 256, 0, stream>>>(x, Wt, Qb, Kb, Vt);
    attn_kernel<<<512, 512, 0, stream>>>(Qb, Kb, Vt, Part);
    merge_kernel<<<256, 256, 0, stream>>>(Part, Ob);
    out_kernel<<<dim3(128, 4), 256, 0, stream>>>(Ob, WoT, bout, out);
}

// Round 4
// 96.088 us; speedup vs baseline: 1.2806x; 1.2806x over previous
//
#include <hip/hip_runtime.h>
#include <hip/hip_bf16.h>

#define N_TOK 8192

typedef float f32x4  __attribute__((ext_vector_type(4)));
typedef float f32x16 __attribute__((ext_vector_type(16)));
typedef short bf16x8 __attribute__((ext_vector_type(8)));
typedef unsigned int u32x4 __attribute__((ext_vector_type(4)));

__device__ inline short f2bf(float f) {
    union { __hip_bfloat16 h; short s; } u;
    u.h = __float2bfloat16(f);
    return u.s;
}
__device__ inline unsigned cvtpk(float lo, float hi) {
    unsigned r;
    asm("v_cvt_pk_bf16_f32 %0, %1, %2" : "=v"(r) : "v"(lo), "v"(hi));
    return r;
}
__device__ inline void plswap(unsigned &a, unsigned &b) {
    asm("v_permlane32_swap_b32 %0, %1" : "+v"(a), "+v"(b));
}

// ---------------- kernel 0: weight convert/transpose (LDS tiled) ----
// grid 256: blocks 0-191 transpose Wqkv [1024][192] -> Wt [192][1024];
// blocks 192-255 transpose Wout [64][1024] -> WoT [1024][64].
__global__ __launch_bounds__(256) void conv_kernel(
    const float* __restrict__ Wqkv,
    const float* __restrict__ Wout,
    __hip_bfloat16* __restrict__ Wt,      // [192][1024]
    __hip_bfloat16* __restrict__ WoT) {   // [1024][64]
    __shared__ float tile[32][33];
    const int t = threadIdx.x;
    const int cc = t & 31, rbase = t >> 5;
    const int b = blockIdx.x;
    if (b < 192) {
        const int r0 = (b & 31) * 32;   // k
        const int c0 = (b >> 5) * 32;   // n
        #pragma unroll
        for (int it = 0; it < 4; ++it) {
            const int rr = rbase + it * 8;
            tile[rr][cc] = Wqkv[(size_t)(r0 + rr) * 192 + c0 + cc];
        }
        __syncthreads();
        #pragma unroll
        for (int it = 0; it < 4; ++it) {
            const int rr = rbase + it * 8;
            Wt[(size_t)(c0 + rr) * 1024 + r0 + cc] = __float2bfloat16(tile[cc][rr]);
        }
    } else {
        const int bb = b - 192;
        const int r0 = (bb & 1) * 32;   // k (rows of Wout)
        const int c0 = (bb >> 1) * 32;  // n
        #pragma unroll
        for (int it = 0; it < 4; ++it) {
            const int rr = rbase + it * 8;
            tile[rr][cc] = Wout[(size_t)(r0 + rr) * 1024 + c0 + cc];
        }
        __syncthreads();
        #pragma unroll
        for (int it = 0; it < 4; ++it) {
            const int rr = rbase + it * 8;
            WoT[(size_t)(c0 + rr) * 64 + r0 + cc] = __float2bfloat16(tile[cc][rr]);
        }
    }
}

// ---------------- kernel 1: qkv = x @ Wqkv -------------------------
// LDS-staged double-buffered GEMM. BM=32, BN=192, BK=64, grid 256, 512 thr.
// 8 waves: wm = w&1 (16-row half), wn = w>>1 (48-col slice = 3 n-tiles).
// XOR chunk swizzle (chunk ^= row&7) on both LDS tiles, write+read sides.
// Q pre-scaled by 0.125*log2(e) (softmax done base-2).
__global__ __launch_bounds__(512) void qkv_kernel(
    const float* __restrict__ x,
    const __hip_bfloat16* __restrict__ Wt,   // [192][1024]
    __hip_bfloat16* __restrict__ Qb,    // [8192][64]
    __hip_bfloat16* __restrict__ Kb,    // [8192][64]
    __hip_bfloat16* __restrict__ Vt) {  // [64][8192]
    __shared__ __hip_bfloat16 sA[2][32 * 64];
    __shared__ __hip_bfloat16 sB[2][192 * 64];
    __shared__ __hip_bfloat16 sV[64][36];
    const int tid = threadIdx.x;
    const int w = tid >> 6, lane = tid & 63;
    const int l16 = lane & 15, lq = lane >> 4;
    const int wm = w & 1, wn = w >> 1;
    const int m0 = blockIdx.x * 32;

    // ---- staging thread-constants ----
    const int ar = tid >> 4;                 // x row 0..31
    const int ac = (tid & 15) >> 1;          // chunk 0..7 (8 bf16 each)
    const int ah = tid & 1;                  // half-chunk (4 elems)
    const float* agp = x + (size_t)(m0 + ar) * 1024 + ac * 8 + ah * 4;
    const int aoff = ar * 64 + ((ac ^ (ar & 7)) * 8) + ah * 4;

    int boff[3];
    const __hip_bfloat16* bgp[3];
    #pragma unroll
    for (int i = 0; i < 3; ++i) {
        const int q = i * 512 + tid;
        const int r = q >> 3, c = q & 7;
        bgp[i] = Wt + (size_t)r * 1024 + c * 8;
        boff[i] = r * 64 + ((c ^ (r & 7)) * 8);
    }

    // ---- fragment read offsets (swizzled) ----
    const int arow = wm * 16 + l16;
    const int aswz0 = arow * 64 + ((lq ^ (arow & 7)) * 8);
    const int aswz1 = arow * 64 + (((4 + lq) ^ (arow & 7)) * 8);
    int bswz0[3], bswz1[3];
    #pragma unroll
    for (int j = 0; j < 3; ++j) {
        const int row = wn * 48 + j * 16 + l16;
        bswz0[j] = row * 64 + ((lq ^ (row & 7)) * 8);
        bswz1[j] = row * 64 + (((4 + lq) ^ (row & 7)) * 8);
    }

    f32x4 acc[3];
    #pragma unroll
    for (int j = 0; j < 3; ++j) acc[j] = (f32x4)0.f;

    float4 areg;
    u32x4 breg[3];

    // prologue: stage K-step 0 into buf 0
    areg = *reinterpret_cast<const float4*>(agp);
    #pragma unroll
    for (int i = 0; i < 3; ++i)
        breg[i] = *reinterpret_cast<const u32x4*>(bgp[i]);
    {
        uint2 aw; aw.x = cvtpk(areg.x, areg.y); aw.y = cvtpk(areg.z, areg.w);
        *reinterpret_cast<uint2*>(&sA[0][aoff]) = aw;
        #pragma unroll
        for (int i = 0; i < 3; ++i)
            *reinterpret_cast<u32x4*>(&sB[0][boff[i]]) = breg[i];
    }
    __syncthreads();

    for (int ks = 0; ks < 16; ++ks) {
        const int cur = ks & 1;
        if (ks < 15) {  // issue global loads for ks+1 early
            areg = *reinterpret_cast<const float4*>(agp + (ks + 1) * 64);
            #pragma unroll
            for (int i = 0; i < 3; ++i)
                breg[i] = *reinterpret_cast<const u32x4*>(bgp[i] + (ks + 1) * 64);
        }
        // compute on buf[cur]
        bf16x8 af0 = *reinterpret_cast<const bf16x8*>(&sA[cur][aswz0]);
        bf16x8 af1 = *reinterpret_cast<const bf16x8*>(&sA[cur][aswz1]);
        #pragma unroll
        for (int j = 0; j < 3; ++j) {
            bf16x8 b0 = *reinterpret_cast<const bf16x8*>(&sB[cur][bswz0[j]]);
            bf16x8 b1 = *reinterpret_cast<const bf16x8*>(&sB[cur][bswz1[j]]);
            acc[j] = __builtin_amdgcn_mfma_f32_16x16x32_bf16(b0, af0, acc[j], 0, 0, 0);
            acc[j] = __builtin_amdgcn_mfma_f32_16x16x32_bf16(b1, af1, acc[j], 0, 0, 0);
        }
        if (ks < 15) {  // write staged regs into the other buffer
            uint2 aw; aw.x = cvtpk(areg.x, areg.y); aw.y = cvtpk(areg.z, areg.w);
            *reinterpret_cast<uint2*>(&sA[cur ^ 1][aoff]) = aw;
            #pragma unroll
            for (int i = 0; i < 3; ++i)
                *reinterpret_cast<u32x4*>(&sB[cur ^ 1][boff[i]]) = breg[i];
        }
        __syncthreads();
    }

    // ---- epilogue: lane holds row m0+wm*16+l16, cols nt*16+4lq..+3 ----
    const int row = m0 + wm * 16 + l16;
    #pragma unroll
    for (int j = 0; j < 3; ++j) {
        const int nt = wn * 3 + j;
        const int nb = nt * 16 + 4 * lq;
        if (nt < 4) {
            short4 qs;
            qs.x = f2bf(acc[j][0] * 0.18033688011112042f);
            qs.y = f2bf(acc[j][1] * 0.18033688011112042f);
            qs.z = f2bf(acc[j][2] * 0.18033688011112042f);
            qs.w = f2bf(acc[j][3] * 0.18033688011112042f);
            *reinterpret_cast<short4*>(Qb + (size_t)row * 64 + nb) = qs;
        } else if (nt < 8) {
            short4 ks4;
            ks4.x = f2bf(acc[j][0]); ks4.y = f2bf(acc[j][1]);
            ks4.z = f2bf(acc[j][2]); ks4.w = f2bf(acc[j][3]);
            *reinterpret_cast<short4*>(Kb + (size_t)row * 64 + (nb - 64)) = ks4;
        } else {
            #pragma unroll
            for (int r = 0; r < 4; ++r)
                sV[nb + r - 128][wm * 16 + l16] = __float2bfloat16(acc[j][r]);
        }
    }
    __syncthreads();
    const int vd = tid >> 3, vm = (tid & 7) * 4;
    short4 vv = *reinterpret_cast<const short4*>(&sV[vd][vm]);
    *reinterpret_cast<short4*>(Vt + (size_t)vd * N_TOK + m0 + vm) = vv;
}

// ---------------- kernel 2: causal flash attention -----------------
// grid 512: (pair p = bid>>2, split s = bid&3). Tiles p and 255-p.
// 8 waves; wave slot = s*8+w handles kv chunks c = slot + 32*i (64 kv each).
// Swapped QK^T (S^T = K Q^T); softmax in-register, base-2; tree reductions.
__global__ __launch_bounds__(512) void attn_kernel(
    const __hip_bfloat16* __restrict__ Qb,
    const __hip_bfloat16* __restrict__ Kb,
    const __hip_bfloat16* __restrict__ Vt,
    float* __restrict__ Part) {  // [256 tiles][4 splits][2112] f32
    __shared__ float sO[8][64][32];
    __shared__ float sM[8][32];
    __shared__ float sL[8][32];
    const int tid = threadIdx.x;
    const int w = tid >> 6, lane = tid & 63;
    const int l31 = lane & 31, hi = lane >> 5;
    const int p = blockIdx.x >> 2, s = blockIdx.x & 3;
    const int slot = s * 8 + w;

    for (int ti = 0; ti < 2; ++ti) {
        const int t = ti ? (255 - p) : p;
        const int q0 = t * 32;
        const int Ct = (q0 + 95) >> 6;   // ceil((q0+32)/64)
        const int qabs = q0 + l31;

        bf16x8 qf[4];
        const __hip_bfloat16* qrow = Qb + (size_t)(q0 + l31) * 64 + 8 * hi;
        #pragma unroll
        for (int c = 0; c < 4; ++c)
            qf[c] = *reinterpret_cast<const bf16x8*>(qrow + c * 16);

        float m = -3.0e38f, l = 0.f;
        f32x16 Oa = (f32x16)0.f, Oc = (f32x16)0.f;

        for (int c = slot; c < Ct; c += 32) {
            const int kv0 = c * 64;
            const __hip_bfloat16* kbase = Kb + (size_t)(kv0 + l31) * 64 + 8 * hi;
            bf16x8 ka[4], kb2[4];
            #pragma unroll
            for (int kc = 0; kc < 4; ++kc) {
                ka[kc]  = *reinterpret_cast<const bf16x8*>(kbase + kc * 16);
                kb2[kc] = *reinterpret_cast<const bf16x8*>(kbase + 32 * 64 + kc * 16);
            }
            f32x16 Sa = (f32x16)0.f, Sb = (f32x16)0.f;
            #pragma unroll
            for (int kc = 0; kc < 4; ++kc)
                Sa = __builtin_amdgcn_mfma_f32_32x32x16_bf16(ka[kc], qf[kc], Sa, 0, 0, 0);
            #pragma unroll
            for (int kc = 0; kc < 4; ++kc)
                Sb = __builtin_amdgcn_mfma_f32_32x32x16_bf16(kb2[kc], qf[kc], Sb, 0, 0, 0);

            if (kv0 + 64 > q0) {  // only near-diagonal chunks need masking
                #pragma unroll
                for (int r = 0; r < 16; ++r) {
                    const int rowk = (r & 3) + 8 * (r >> 2) + 4 * hi;
                    if (kv0 + rowk > qabs)      Sa[r] = -1.0e30f;
                    if (kv0 + 32 + rowk > qabs) Sb[r] = -1.0e30f;
                }
            }

            // tree max (depth 5)
            float v8[8];
            #pragma unroll
            for (int j = 0; j < 8; ++j)
                v8[j] = fmaxf(fmaxf(Sa[2*j], Sa[2*j+1]), fmaxf(Sb[2*j], Sb[2*j+1]));
            #pragma unroll
            for (int j = 0; j < 4; ++j) v8[j] = fmaxf(v8[j], v8[j+4]);
            float mx = fmaxf(fmaxf(v8[0], v8[2]), fmaxf(v8[1], v8[3]));
            mx = fmaxf(mx, __shfl_xor(mx, 32));
            const float mnew = fmaxf(m, mx);
            const float fac = exp2f(m - mnew);
            #pragma unroll
            for (int r = 0; r < 16; ++r) Sa[r] = exp2f(Sa[r] - mnew);
            #pragma unroll
            for (int r = 0; r < 16; ++r) Sb[r] = exp2f(Sb[r] - mnew);
            // tree sum
            float s8[8];
            #pragma unroll
            for (int j = 0; j < 8; ++j)
                s8[j] = (Sa[2*j] + Sa[2*j+1]) + (Sb[2*j] + Sb[2*j+1]);
            #pragma unroll
            for (int j = 0; j < 4; ++j) s8[j] += s8[j+4];
            float ps = (s8[0] + s8[2]) + (s8[1] + s8[3]);
            ps += __shfl_xor(ps, 32);
            l = l * fac + ps;
            m = mnew;
            #pragma unroll
            for (int r = 0; r < 16; ++r) { Oa[r] *= fac; Oc[r] *= fac; }

            // P^T -> bf16 B-fragments via cvt_pk + permlane32_swap (T12)
            bf16x8 F0, F1, F2, F3;
            {
                unsigned a0 = cvtpk(Sa[0], Sa[1]),  a1 = cvtpk(Sa[2], Sa[3]);
                unsigned a2 = cvtpk(Sa[4], Sa[5]),  a3 = cvtpk(Sa[6], Sa[7]);
                plswap(a0, a2); plswap(a1, a3);
                u32x4 w0; w0[0]=a0; w0[1]=a1; w0[2]=a2; w0[3]=a3;
                F0 = __builtin_bit_cast(bf16x8, w0);
                unsigned b0 = cvtpk(Sa[8], Sa[9]),  b1 = cvtpk(Sa[10], Sa[11]);
                unsigned b2 = cvtpk(Sa[12], Sa[13]), b3 = cvtpk(Sa[14], Sa[15]);
                plswap(b0, b2); plswap(b1, b3);
                u32x4 w1; w1[0]=b0; w1[1]=b1; w1[2]=b2; w1[3]=b3;
                F1 = __builtin_bit_cast(bf16x8, w1);
                unsigned c0 = cvtpk(Sb[0], Sb[1]),  c1 = cvtpk(Sb[2], Sb[3]);
                unsigned c2 = cvtpk(Sb[4], Sb[5]),  c3 = cvtpk(Sb[6], Sb[7]);
                plswap(c0, c2); plswap(c1, c3);
                u32x4 w2; w2[0]=c0; w2[1]=c1; w2[2]=c2; w2[3]=c3;
                F2 = __builtin_bit_cast(bf16x8, w2);
                unsigned d0 = cvtpk(Sb[8], Sb[9]),  d1 = cvtpk(Sb[10], Sb[11]);
                unsigned d2 = cvtpk(Sb[12], Sb[13]), d3 = cvtpk(Sb[14], Sb[15]);
                plswap(d0, d2); plswap(d1, d3);
                u32x4 w3; w3[0]=d0; w3[1]=d1; w3[2]=d2; w3[3]=d3;
                F3 = __builtin_bit_cast(bf16x8, w3);
            }
            const __hip_bfloat16* vbase = Vt + (size_t)l31 * N_TOK + kv0 + 8 * hi;
            bf16x8 Fa[4] = {F0, F1, F2, F3};
            #pragma unroll
            for (int ks = 0; ks < 4; ++ks) {
                bf16x8 v0 = *reinterpret_cast<const bf16x8*>(vbase + ks * 16);
                bf16x8 v1 = *reinterpret_cast<const bf16x8*>(vbase + (size_t)32 * N_TOK + ks * 16);
                Oa = __builtin_amdgcn_mfma_f32_32x32x16_bf16(v0, Fa[ks], Oa, 0, 0, 0);
                Oc = __builtin_amdgcn_mfma_f32_32x32x16_bf16(v1, Fa[ks], Oc, 0, 0, 0);
            }
        }

        if (hi == 0) { sM[w][l31] = m; sL[w][l31] = l; }
        #pragma unroll
        for (int r = 0; r < 16; ++r) {
            const int d = (r & 3) + 8 * (r >> 2) + 4 * hi;
            sO[w][d][l31]      = Oa[r];
            sO[w][d + 32][l31] = Oc[r];
        }
        __syncthreads();

        float* pb = Part + (size_t)(t * 4 + s) * 2112;
        for (int e = tid; e < 2048; e += 512) {
            const int d = e >> 5, qq = e & 31;
            float mb = -3.0e38f;
            #pragma unroll
            for (int wi = 0; wi < 8; ++wi) mb = fmaxf(mb, sM[wi][qq]);
            float lb = 0.f, ob = 0.f;
            #pragma unroll
            for (int wi = 0; wi < 8; ++wi) {
                const float sc = exp2f(sM[wi][qq] - mb);
                lb += sL[wi][qq] * sc;
                ob += sO[wi][d][qq] * sc;
            }
            pb[e] = ob;
            if (d == 0) { pb[2048 + qq] = mb; pb[2080 + qq] = lb; }
        }
        __syncthreads();
    }
}

// ---------------- kernel 2b: merge the 4 kv-split partials ---------
__global__ __launch_bounds__(256) void merge_kernel(
    const float* __restrict__ Part, __hip_bfloat16* __restrict__ Ob) {
    const int t = blockIdx.x, q0 = t * 32;
    const float* pp = Part + (size_t)(t * 4) * 2112;
    for (int e = threadIdx.x; e < 2048; e += 256) {
        const int qq = e >> 6, d = e & 63;
        float mm = -3.0e38f;
        #pragma unroll
        for (int si = 0; si < 4; ++si) mm = fmaxf(mm, pp[si * 2112 + 2048 + qq]);
        float ll = 0.f, oo = 0.f;
        #pragma unroll
        for (int si = 0; si < 4; ++si) {
            const float sc = exp2f(pp[si * 2112 + 2048 + qq] - mm);
            ll += pp[si * 2112 + 2080 + qq] * sc;
            oo += pp[si * 2112 + d * 32 + qq] * sc;
        }
        Ob[(size_t)(q0 + qq) * 64 + d] = __float2bfloat16(oo / ll);
    }
}

// ---------------- kernel 3: out = O @ Wout + bout ------------------
// Swapped mfma(Wfrag, Ofrag): lane owns 4 consecutive cols of one row
// -> one float4 store per tile per lane.
__global__ __launch_bounds__(256) void out_kernel(
    const __hip_bfloat16* __restrict__ Ob,
    const __hip_bfloat16* __restrict__ WoT,
    const float* __restrict__ bout,
    float* __restrict__ out) {
    const int tid = threadIdx.x;
    const int w = tid >> 6, lane = tid & 63;
    const int l16 = lane & 15, lq = lane >> 4;
    const int m0 = blockIdx.x * 64 + w * 16;
    const int n0 = blockIdx.y * 256;

    const __hip_bfloat16* orow = Ob + (size_t)(m0 + l16) * 64;
    bf16x8 a0 = *reinterpret_cast<const bf16x8*>(orow + 8 * lq);
    bf16x8 a1 = *reinterpret_cast<const bf16x8*>(orow + 32 + 8 * lq);

    const int row = m0 + l16;
    for (int nt = 0; nt < 16; ++nt) {
        const __hip_bfloat16* wrow = WoT + (size_t)(n0 + nt * 16 + l16) * 64;
        bf16x8 b0 = *reinterpret_cast<const bf16x8*>(wrow + 8 * lq);
        bf16x8 b1 = *reinterpret_cast<const bf16x8*>(wrow + 32 + 8 * lq);
        f32x4 acc = (f32x4)0.f;
        acc = __builtin_amdgcn_mfma_f32_16x16x32_bf16(b0, a0, acc, 0, 0, 0);
        acc = __builtin_amdgcn_mfma_f32_16x16x32_bf16(b1, a1, acc, 0, 0, 0);
        const int nb = n0 + nt * 16 + 4 * lq;
        float4 bb = *reinterpret_cast<const float4*>(bout + nb);
        float4 res;
        res.x = acc[0] + bb.x; res.y = acc[1] + bb.y;
        res.z = acc[2] + bb.z; res.w = acc[3] + bb.w;
        *reinterpret_cast<float4*>(out + (size_t)row * 1024 + nb) = res;
    }
}

// ---------------- launch -------------------------------------------
extern "C" void kernel_launch(void* const* d_in, const int* in_sizes, int n_in,
                              void* d_out, int out_size, void* d_ws, size_t ws_size,
                              hipStream_t stream) {
    const float* x    = (const float*)d_in[0];
    const float* Wqkv = (const float*)d_in[1];
    const float* Wout = (const float*)d_in[2];
    const float* bout = (const float*)d_in[3];
    float* out = (float*)d_out;

    char* ws = (char*)d_ws;
    __hip_bfloat16* Wt  = (__hip_bfloat16*)(ws);                 // 393216 B
    __hip_bfloat16* WoT = (__hip_bfloat16*)(ws + 393216);        // 131072 B
    __hip_bfloat16* Qb  = (__hip_bfloat16*)(ws + 524288);        // 1 MiB
    __hip_bfloat16* Kb  = (__hip_bfloat16*)(ws + 1572864);       // 1 MiB
    __hip_bfloat16* Vt  = (__hip_bfloat16*)(ws + 2621440);       // 1 MiB
    __hip_bfloat16* Ob  = (__hip_bfloat16*)(ws + 3670016);       // 1 MiB
    float*          Part = (float*)(ws + 4718592);               // 8.65 MB

    conv_kernel<<<256, 256, 0, stream>>>(Wqkv, Wout, Wt, WoT);
    qkv_kernel<<<256, 512, 0, stream>>>(x, Wt, Qb, Kb, Vt);
    attn_kernel<<<512, 512, 0, stream>>>(Qb, Kb, Vt, Part);
    merge_kernel<<<256, 256, 0, stream>>>(Part, Ob);
    out_kernel<<<dim3(128, 4), 256, 0, stream>>>(Ob, WoT, bout, out);
}